// Round 6
// baseline (133.765 us; speedup 1.0000x reference)
//
#include <hip/hip_runtime.h>
#include <math.h>

// Problem constants (match reference)
#define NN 256
#define GSZ 512
#define GG (GSZ * GSZ)
#define BC 16            // B*C
#define MM 65536
#define ALPHA_C 14.04f   // 2.34 * W
#define WKER 6
#define PI_F 3.14159265358979f
#define KSCALE 81.48733086305042f  // GSZ / (2*pi)

// Gather tiling: 32x32 grid cells per tile -> 16x16 = 256 tiles, ~256 pts/tile
#define NTILE 256
#define CAP 352          // mean 256, sd 16 -> +6 sigma
#define TW 37            // region rows (32 + 5)
#define TCW 38           // region col pitch (37 + 1)
#define BCH 4            // bc images per gather block (tile split over 4 blocks)

// ---------------- device math helpers ----------------

// Modified Bessel I0, Abramowitz & Stegun 9.8.1 / 9.8.2 (rel err < 2e-7)
__device__ __forceinline__ float bessel_i0(float x) {
    if (x < 3.75f) {
        float t = x * (1.0f / 3.75f);
        float t2 = t * t;
        return 1.0f + t2 * (3.5156229f + t2 * (3.0899424f + t2 * (1.2067492f +
                     t2 * (0.2659732f + t2 * (0.0360768f + t2 * 0.0045813f)))));
    } else {
        float t = 3.75f / x;
        float p = 0.39894228f + t * (0.01328592f + t * (0.00225319f + t * (-0.00157565f +
                  t * (0.00916281f + t * (-0.02057706f + t * (0.02635537f +
                  t * (-0.01647633f + t * 0.00392377f)))))));
        return p * __expf(x) * rsqrtf(x);
    }
}

__device__ __forceinline__ float kb_weight(float d) {
    float r = d * (2.0f / (float)WKER);
    float u = 1.0f - r * r;
    if (u <= 0.0f) return 0.0f;
    return bessel_i0(ALPHA_C * sqrtf(u)) * (1.0f / (float)WKER);
}

// 1 / kb_ft(t); for |t|<=0.25 s2>0 always -> sinh branch only.
__device__ __forceinline__ float kb_ft_inv(float t) {
    float a = PI_F * (float)WKER * t;
    float s2 = ALPHA_C * ALPHA_C - a * a;
    float z = sqrtf(fabsf(s2)) + 1e-12f;
    float sh = 0.5f * (__expf(z) - __expf(-z));
    return z / sh;
}

// ---------------- FFT kernels (twiddle-table radix-2) ----------------
// tw[k] = exp(-i*pi*k/256); stage s (half = 1<<(s-1)) uses tw[pos << (9-s)].

__global__ void k_fft_row(const float* __restrict__ x, float2* __restrict__ grid) {
    __shared__ float re[GSZ];
    __shared__ float im[GSZ];
    __shared__ float twc[256], tws[256];
    int b = blockIdx.x;
    int bc = b >> 8;
    int ridx = b & 255;
    int r = (ridx < 128) ? ridx : ridx + 256;
    int r_img = ridx ^ 128;
    int t = threadIdx.x;
    {
        float ang = -PI_F * (float)t * (1.0f / 256.0f);
        float sn, cs;
        __sincosf(ang, &sn, &cs);
        twc[t] = cs; tws[t] = sn;
    }
    float scx = kb_ft_inv((float)(r_img - 128) * (1.0f / (float)GSZ));
    int y = t ^ 128;
    float scy = kb_ft_inv((float)(y - 128) * (1.0f / (float)GSZ));
    float v = x[((size_t)bc * NN + (size_t)r_img) * NN + y] * scx * scy;
    int i_valid = (t < 128) ? t : t + 256;
    int i_zero  = (t < 128) ? t + 256 : t;
    int brv = (int)(__brev((unsigned)i_valid) >> 23);
    int brz = (int)(__brev((unsigned)i_zero) >> 23);
    re[brv] = v;    im[brv] = 0.0f;
    re[brz] = 0.0f; im[brz] = 0.0f;
    __syncthreads();
#pragma unroll
    for (int s = 1; s <= 9; ++s) {
        int half = 1 << (s - 1);
        int pos = t & (half - 1);
        int j0 = ((t >> (s - 1)) << s) + pos;
        int j1 = j0 + half;
        int k = pos << (9 - s);
        float cs = twc[k], sn = tws[k];
        float xr = re[j1], xi = im[j1];
        float tr = xr * cs - xi * sn;
        float ti = xr * sn + xi * cs;
        float ur = re[j0], ui = im[j0];
        re[j0] = ur + tr;
        im[j0] = ui + ti;
        re[j1] = ur - tr;
        im[j1] = ui - ti;
        __syncthreads();
    }
    size_t base = (size_t)bc * GG + (size_t)r * GSZ;
    grid[base + t]       = make_float2(re[t], im[t]);
    grid[base + t + 256] = make_float2(re[t + 256], im[t + 256]);
}

// Column pass: 16 adjacent columns per block (full 128B-line coalescing).
#define CP2 517
__global__ void __launch_bounds__(256) k_fft_col(float2* __restrict__ grid) {
    __shared__ float re[16][CP2];
    __shared__ float im[16][CP2];
    __shared__ float twc[256], tws[256];
    int b = blockIdx.x;          // 16 images * 32 slabs
    int bc = b >> 5;
    int c0 = (b & 31) << 4;
    size_t base = (size_t)bc * GG + (size_t)c0;
    int t = threadIdx.x;
    {
        float ang = -PI_F * (float)t * (1.0f / 256.0f);
        float sn, cs;
        __sincosf(ang, &sn, &cs);
        twc[t] = cs; tws[t] = sn;
    }
#pragma unroll
    for (int k = 0; k < 32; ++k) {
        int e = t + (k << 8);
        int row = e >> 4, col = e & 15;
        float2 v = make_float2(0.0f, 0.0f);
        if (row < 128 || row >= 384)
            v = grid[base + (size_t)row * GSZ + col];
        int br = (int)(__brev((unsigned)row) >> 23);
        re[col][br] = v.x;
        im[col][br] = v.y;
    }
    __syncthreads();
    int ct = t & 15;   // column
    int b0 = t >> 4;   // butterfly base 0..15
#pragma unroll
    for (int s = 1; s <= 9; ++s) {
        int half = 1 << (s - 1);
#pragma unroll
        for (int k = 0; k < 16; ++k) {
            int bf = b0 + (k << 4);          // butterfly id 0..255
            int pos = bf & (half - 1);
            int j0 = ((bf >> (s - 1)) << s) + pos;
            int j1 = j0 + half;
            int tk = pos << (9 - s);
            float cs = twc[tk], sn = tws[tk];
            float xr = re[ct][j1], xi = im[ct][j1];
            float tr = xr * cs - xi * sn;
            float ti = xr * sn + xi * cs;
            float ur = re[ct][j0], ui = im[ct][j0];
            re[ct][j0] = ur + tr;
            im[ct][j0] = ui + ti;
            re[ct][j1] = ur - tr;
            im[ct][j1] = ui - ti;
        }
        __syncthreads();
    }
#pragma unroll
    for (int k = 0; k < 32; ++k) {
        int e = t + (k << 8);
        int row = e >> 4, col = e & 15;
        grid[base + (size_t)row * GSZ + col] = make_float2(re[col][row], im[col][row]);
    }
}

// ---------------- binning (single pass, fixed-capacity buckets) ----------------

__global__ void k_bin(const float* __restrict__ kt, unsigned* __restrict__ cnt,
                      unsigned short* __restrict__ ubuf) {
    int m = blockIdx.x * blockDim.x + threadIdx.x;
    float tmx = kt[m] * KSCALE;
    float tmy = kt[MM + m] * KSCALE;
    int ibx = (int)floorf(tmx) & (GSZ - 1);
    int iby = (int)floorf(tmy) & (GSZ - 1);
    int tile = ((ibx >> 5) << 4) | (iby >> 5);
    unsigned slot = atomicAdd(&cnt[tile], 1u);
    if (slot < CAP) ubuf[(size_t)tile * CAP + slot] = (unsigned short)m;
}

// ---------------- LDS-staged tile gather ----------------
// blockIdx.x = tile*4 + q; block covers bc images [4q, 4q+4) of one 32x32 tile.
// Phase A: stage 4 x 37x38 float2 region (45KB). Phase B: per-point weights
// once into LDS. Phase C: wave g handles bc0+g; lanes stripe points.
__global__ void __launch_bounds__(256) k_gather_tile(
    const float2* __restrict__ Xk, const float* __restrict__ kt,
    const unsigned* __restrict__ cnt, const unsigned short* __restrict__ ubuf,
    float2* __restrict__ out) {
    __shared__ float2 lds_d[BCH][TW][TCW];  // 44992 B
    __shared__ float wts[CAP][13];          // 18304 B
    __shared__ int lxy[CAP];                // 1408 B
    int b = blockIdx.x;
    int tile = b >> 2;
    int bc0 = (b & 3) * BCH;
    int tx0 = (tile >> 4) << 5;
    int ty0 = (tile & 15) << 5;
    int t = threadIdx.x;
    // Phase A: stage
    for (int idx = t; idx < BCH * TW * TCW; idx += 256) {
        int bc = idx / (TW * TCW);
        int rem = idx - bc * (TW * TCW);
        int r = rem / TCW;
        int c = rem - r * TCW;
        int row = (tx0 - 2 + r) & (GSZ - 1);
        int col = (ty0 - 2 + c) & (GSZ - 1);
        lds_d[bc][r][c] = Xk[(size_t)(bc0 + bc) * GG + (size_t)row * GSZ + col];
    }
    int n = (int)cnt[tile];
    if (n > CAP) n = CAP;
    // Phase B: weights (once per point)
    for (int p = t; p < n; p += 256) {
        int m = (int)ubuf[(size_t)tile * CAP + p];
        float tmx = kt[m] * KSCALE;
        float tmy = kt[MM + m] * KSCALE;
        float bx = floorf(tmx), by = floorf(tmy);
#pragma unroll
        for (int o = 0; o < 6; ++o) {
            float offv = (float)(o - 2);
            wts[p][o]     = kb_weight(tmx - (bx + offv));
            wts[p][6 + o] = kb_weight(tmy - (by + offv));
        }
        int lx = (int)bx & 31;
        int ly = (int)by & 31;
        lxy[p] = (lx << 8) | ly;
    }
    __syncthreads();
    // Phase C: compute. Wave g -> bc0+g; lanes stripe points.
    int g = t >> 6;
    size_t obase = (size_t)(bc0 + g) * MM;
    for (int s = (t & 63); s < n; s += 64) {
        int m = (int)ubuf[(size_t)tile * CAP + s];
        float w0v[6], w1v[6];
#pragma unroll
        for (int o = 0; o < 6; ++o) {
            w0v[o] = wts[s][o];
            w1v[o] = wts[s][6 + o];
        }
        int lc = lxy[s];
        int lx = lc >> 8, ly = lc & 255;
        float ar = 0.0f, ai = 0.0f;
#pragma unroll
        for (int ii = 0; ii < 6; ++ii) {
            float wi = w0v[ii];
#pragma unroll
            for (int j = 0; j < 6; ++j) {
                float wv = wi * w1v[j];
                float2 va = lds_d[g][lx + ii][ly + j];
                ar = fmaf(wv, va.x, ar);
                ai = fmaf(wv, va.y, ai);
            }
        }
        out[obase + m] = make_float2(ar, ai);
    }
}

// Fallback gather if ws is too small.
__global__ void k_gather(const float2* __restrict__ Xk, const float* __restrict__ kt,
                         float2* __restrict__ out) {
    int tid = blockIdx.x * blockDim.x + threadIdx.x;
    int m = tid & (MM - 1);
    int bc = tid >> 16;
    float tmx = kt[m] * KSCALE;
    float tmy = kt[MM + m] * KSCALE;
    float bx = floorf(tmx), by = floorf(tmy);
    int ibx = (int)bx, iby = (int)by;
    float w0[6], w1[6];
    int ix[6], iy[6];
#pragma unroll
    for (int o = 0; o < 6; ++o) {
        float offv = (float)(o - 2);
        w0[o] = kb_weight(tmx - (bx + offv));
        w1[o] = kb_weight(tmy - (by + offv));
        ix[o] = (ibx + (o - 2) + GSZ) & (GSZ - 1);
        iy[o] = (iby + (o - 2) + GSZ) & (GSZ - 1);
    }
    const float2* img = Xk + (size_t)bc * GG;
    float ar = 0.0f, ai = 0.0f;
#pragma unroll
    for (int i = 0; i < 6; ++i) {
        const float2* rowp = img + (size_t)ix[i] * GSZ;
        float wi = w0[i];
#pragma unroll
        for (int j = 0; j < 6; ++j) {
            float2 v = rowp[iy[j]];
            float wv = wi * w1[j];
            ar = fmaf(wv, v.x, ar);
            ai = fmaf(wv, v.y, ai);
        }
    }
    out[(size_t)bc * MM + m] = make_float2(ar, ai);
}

// ---------------- launch ----------------

extern "C" void kernel_launch(void* const* d_in, const int* in_sizes, int n_in,
                              void* d_out, int out_size, void* d_ws, size_t ws_size,
                              hipStream_t stream) {
    const float* x = (const float*)d_in[0];
    const float* kt = (const float*)d_in[1];
    float2* out = (float2*)d_out;
    char* ws = (char*)d_ws;

    const size_t GRID_BYTES = (size_t)BC * GG * sizeof(float2);      // 33.55 MB
    const size_t CNT_BYTES = NTILE * sizeof(unsigned);               // 1 KB
    const size_t UBUF_BYTES = (size_t)NTILE * CAP * sizeof(unsigned short); // 176 KB
    float2* grid = (float2*)ws;
    unsigned* cnt = (unsigned*)(ws + GRID_BYTES);
    unsigned short* ubuf = (unsigned short*)(ws + GRID_BYTES + CNT_BYTES);
    const size_t NEED = GRID_BYTES + CNT_BYTES + UBUF_BYTES;

    if (ws_size >= NEED) {
        hipMemsetAsync(cnt, 0, CNT_BYTES, stream);
        k_bin<<<MM / 256, 256, 0, stream>>>(kt, cnt, ubuf);
        k_fft_row<<<BC * 256, 256, 0, stream>>>(x, grid);
        k_fft_col<<<BC * (GSZ / 16), 256, 0, stream>>>(grid);
        k_gather_tile<<<NTILE * 4, 256, 0, stream>>>(grid, kt, cnt, ubuf, out);
    } else {
        k_fft_row<<<BC * 256, 256, 0, stream>>>(x, grid);
        k_fft_col<<<BC * (GSZ / 16), 256, 0, stream>>>(grid);
        k_gather<<<(BC * MM) / 256, 256, 0, stream>>>(grid, kt, out);
    }
}

// Round 7
// 95.207 us; speedup vs baseline: 1.4050x; 1.4050x over previous
//
#include <hip/hip_runtime.h>
#include <math.h>

// Problem constants (match reference)
#define NN 256
#define GSZ 512
#define GG (GSZ * GSZ)
#define BC 16            // B*C
#define MM 65536
#define ALPHA_C 14.04f   // 2.34 * W
#define WKER 6
#define PI_F 3.14159265358979f
#define RC2 0.70710678118654752f
#define KSCALE 81.48733086305042f  // GSZ / (2*pi)

// Gather tiling (round-4 config: best measured)
#define CAP 160          // bucket capacity (mean 64, sd 8)
#define TW 21            // stencil region rows per tile (16 + 5)
#define TCW 22           // stored cols (21 + 1 pitch)
#define BCH 8            // bc images per gather block (tile split over 2 blocks)

// ---------------- device math helpers ----------------

__device__ __forceinline__ float bessel_i0(float x) {
    if (x < 3.75f) {
        float t = x * (1.0f / 3.75f);
        float t2 = t * t;
        return 1.0f + t2 * (3.5156229f + t2 * (3.0899424f + t2 * (1.2067492f +
                     t2 * (0.2659732f + t2 * (0.0360768f + t2 * 0.0045813f)))));
    } else {
        float t = 3.75f / x;
        float p = 0.39894228f + t * (0.01328592f + t * (0.00225319f + t * (-0.00157565f +
                  t * (0.00916281f + t * (-0.02057706f + t * (0.02635537f +
                  t * (-0.01647633f + t * 0.00392377f)))))));
        return p * __expf(x) * rsqrtf(x);
    }
}

__device__ __forceinline__ float kb_weight(float d) {
    float r = d * (2.0f / (float)WKER);
    float u = 1.0f - r * r;
    if (u <= 0.0f) return 0.0f;
    return bessel_i0(ALPHA_C * sqrtf(u)) * (1.0f / (float)WKER);
}

__device__ __forceinline__ float kb_ft_inv(float t) {
    float a = PI_F * (float)WKER * t;
    float s2 = ALPHA_C * ALPHA_C - a * a;
    float z = sqrtf(fabsf(s2)) + 1e-12f;
    float sh = 0.5f * (__expf(z) - __expf(-z));
    return z / sh;
}

__device__ __forceinline__ void cmul(float& zr, float& zi, float wr, float wi) {
    float r = zr * wr - zi * wi;
    zi = zr * wi + zi * wr;
    zr = r;
}

// ---------------- radix-8 stage (in-place on one 512-pt plane pair) ----------
// Data lives at phi(i) = i + (i>>3). Stage combines 8 sub-DFTs of length L.
// Butterfly j in [0,64): pos = j%L, base = (j-pos)*8 + pos, indices base + r*L.
template <int L>
__device__ __forceinline__ void radix8_stage(float* pr, float* pi_, int j) {
    int pos = j & (L - 1);
    int base = (j - pos) * 8 + pos;
    float ar[8], ai[8];
#pragma unroll
    for (int r = 0; r < 8; ++r) {
        int idx = base + r * L;
        int ph = idx + (idx >> 3);
        ar[r] = pr[ph];
        ai[r] = pi_[ph];
    }
    if (L > 1) {
        float th = (float)pos * (-PI_F / (4.0f * (float)L));
        float s1, c1;
        __sincosf(th, &s1, &c1);
        float wr = c1, wi = s1;
#pragma unroll
        for (int r = 1; r < 8; ++r) {
            cmul(ar[r], ai[r], wr, wi);
            float nr = wr * c1 - wi * s1;
            wi = wr * s1 + wi * c1;
            wr = nr;
        }
    }
    // 8-point DFT (DIT split even/odd into two 4-pt DFTs)
    float s0r = ar[0] + ar[4], s0i = ai[0] + ai[4];
    float d0r = ar[0] - ar[4], d0i = ai[0] - ai[4];
    float s1r = ar[2] + ar[6], s1i = ai[2] + ai[6];
    float d1r = ar[2] - ar[6], d1i = ai[2] - ai[6];
    float E0r = s0r + s1r, E0i = s0i + s1i;
    float E2r = s0r - s1r, E2i = s0i - s1i;
    float E1r = d0r + d1i, E1i = d0i - d1r;   // d0 - i*d1
    float E3r = d0r - d1i, E3i = d0i + d1r;   // d0 + i*d1
    float u0r = ar[1] + ar[5], u0i = ai[1] + ai[5];
    float v0r = ar[1] - ar[5], v0i = ai[1] - ai[5];
    float u1r = ar[3] + ar[7], u1i = ai[3] + ai[7];
    float v1r = ar[3] - ar[7], v1i = ai[3] - ai[7];
    float O0r = u0r + u1r, O0i = u0i + u1i;
    float O2r = u0r - u1r, O2i = u0i - u1i;
    float O1r = v0r + v1i, O1i = v0i - v1r;
    float O3r = v0r - v1i, O3i = v0i + v1r;
    float t1r = RC2 * (O1r + O1i), t1i = RC2 * (O1i - O1r);   // w8^1 * O1
    float t2r = O2i,               t2i = -O2r;                // w8^2 * O2
    float t3r = RC2 * (O3i - O3r), t3i = -RC2 * (O3r + O3i);  // w8^3 * O3
    float xr[8], xi[8];
    xr[0] = E0r + O0r; xi[0] = E0i + O0i;
    xr[4] = E0r - O0r; xi[4] = E0i - O0i;
    xr[1] = E1r + t1r; xi[1] = E1i + t1i;
    xr[5] = E1r - t1r; xi[5] = E1i - t1i;
    xr[2] = E2r + t2r; xi[2] = E2i + t2i;
    xr[6] = E2r - t2r; xi[6] = E2i - t2i;
    xr[3] = E3r + t3r; xi[3] = E3i + t3i;
    xr[7] = E3r - t3r; xi[7] = E3i - t3i;
#pragma unroll
    for (int q = 0; q < 8; ++q) {
        int idx = base + q * L;
        int ph = idx + (idx >> 3);
        pr[ph] = xr[q];
        pi_[ph] = xi[q];
    }
}

// ---------------- FFT kernels (radix-8, 3 stages) ----------------

// Row pass: fused deapodize + roll + zero-pad. Wave per row, 4 rows per block.
#define LDSP 576
__global__ void __launch_bounds__(256) k_fft_row(const float* __restrict__ x,
                                                 float2* __restrict__ grid) {
    __shared__ float re[4][LDSP], im[4][LDSP];   // 18432 B
    int b = blockIdx.x;            // 1024 blocks = 16 bc * 64 row-groups
    int t = threadIdx.x;
    int w = t >> 6;                // wave = row within block
    int l = t & 63;
    int rg = (b & 63) * 4 + w;     // ridx 0..255
    int bc = b >> 6;
    int r = (rg < 128) ? rg : rg + 256;
    int r_img = rg ^ 128;
    float scx = kb_ft_inv((float)(r_img - 128) * (1.0f / (float)GSZ));
    const float* xrow = x + ((size_t)bc * NN + (size_t)r_img) * NN;
    // load + deapodize + digit-reverse (base 8)
#pragma unroll
    for (int e = 0; e < 8; ++e) {
        int i = e * 64 + l;
        float v = 0.0f;
        if (i < 128 || i >= 384) {
            int y = (i + 128) & (GSZ - 1);
            float scy = kb_ft_inv((float)(y - 128) * (1.0f / (float)GSZ));
            v = xrow[y] * scx * scy;
        }
        int rev = (l & 7) * 64 + (l >> 3) * 8 + e;
        int ph = rev + (rev >> 3);
        re[w][ph] = v;
        im[w][ph] = 0.0f;
    }
    __syncthreads();
    radix8_stage<1>(re[w], im[w], l);
    __syncthreads();
    radix8_stage<8>(re[w], im[w], l);
    __syncthreads();
    radix8_stage<64>(re[w], im[w], l);
    __syncthreads();
    size_t gbase = (size_t)bc * GG + (size_t)r * GSZ;
#pragma unroll
    for (int e = 0; e < 8; ++e) {
        int k = e * 64 + l;
        int ph = k + (k >> 3);
        grid[gbase + k] = make_float2(re[w][ph], im[w][ph]);
    }
}

// Column pass: 16-column slabs (full-line coalescing), zero rows skipped.
#define CSTR 577
__global__ void __launch_bounds__(256) k_fft_col(float2* __restrict__ grid) {
    __shared__ float re[16][CSTR], im[16][CSTR];  // 73856 B
    int b = blockIdx.x;      // 512 blocks = 16 bc * 32 col-groups
    int bc = b >> 5;
    int c0 = (b & 31) << 4;
    size_t base = (size_t)bc * GG + (size_t)c0;
    int t = threadIdx.x;
#pragma unroll
    for (int it = 0; it < 32; ++it) {
        int idx = it * 256 + t;
        int row = idx >> 4, col = idx & 15;
        float2 v = make_float2(0.0f, 0.0f);
        if (row < 128 || row >= 384)
            v = grid[base + (size_t)row * GSZ + col];
        int rev = (row & 7) * 64 + ((row >> 3) & 7) * 8 + (row >> 6);
        int ph = rev + (rev >> 3);
        re[col][ph] = v.x;
        im[col][ph] = v.y;
    }
    __syncthreads();
    int col = t & 15, jg = t >> 4;   // 16 j-groups of 4 butterflies
#pragma unroll
    for (int k = 0; k < 4; ++k) radix8_stage<1>(re[col], im[col], jg + 16 * k);
    __syncthreads();
#pragma unroll
    for (int k = 0; k < 4; ++k) radix8_stage<8>(re[col], im[col], jg + 16 * k);
    __syncthreads();
#pragma unroll
    for (int k = 0; k < 4; ++k) radix8_stage<64>(re[col], im[col], jg + 16 * k);
    __syncthreads();
#pragma unroll
    for (int it = 0; it < 32; ++it) {
        int idx = it * 256 + t;
        int row = idx >> 4, c = idx & 15;
        int ph = row + (row >> 3);
        grid[base + (size_t)row * GSZ + c] = make_float2(re[c][ph], im[c][ph]);
    }
}

// ---------------- binning (single pass, fixed-capacity buckets) ----------------

__global__ void k_bin(const float* __restrict__ kt, unsigned* __restrict__ cnt,
                      unsigned short* __restrict__ ubuf) {
    int m = blockIdx.x * blockDim.x + threadIdx.x;
    float tmx = kt[m] * KSCALE;
    float tmy = kt[MM + m] * KSCALE;
    int ibx = (int)floorf(tmx) & (GSZ - 1);
    int iby = (int)floorf(tmy) & (GSZ - 1);
    int tile = ((ibx >> 4) << 5) | (iby >> 4);
    unsigned slot = atomicAdd(&cnt[tile], 1u);
    if (slot < CAP) ubuf[(size_t)tile * CAP + slot] = (unsigned short)m;
}

// ---------------- LDS-staged tile gather (round-4 config) ----------------
__global__ void __launch_bounds__(256) k_gather_tile(
    const float2* __restrict__ Xk, const float* __restrict__ kt,
    const unsigned* __restrict__ cnt, const unsigned short* __restrict__ ubuf,
    float2* __restrict__ out) {
    __shared__ float2 lds_d[BCH][TW][TCW];  // 29568 B
    __shared__ float wts[CAP][13];          // 8320 B
    __shared__ int lxy[CAP];                // 640 B
    int b = blockIdx.x;
    int tile = b >> 1;
    int bc0 = (b & 1) * BCH;
    int tx0 = (tile >> 5) << 4;
    int ty0 = (tile & 31) << 4;
    int t = threadIdx.x;
    for (int idx = t; idx < BCH * TW * TCW; idx += 256) {
        int bc = idx / (TW * TCW);
        int rem = idx - bc * (TW * TCW);
        int r = rem / TCW;
        int c = rem - r * TCW;
        int row = (tx0 - 2 + r) & (GSZ - 1);
        int col = (ty0 - 2 + c) & (GSZ - 1);
        lds_d[bc][r][c] = Xk[(size_t)(bc0 + bc) * GG + (size_t)row * GSZ + col];
    }
    int n = (int)cnt[tile];
    if (n > CAP) n = CAP;
    if (t < n) {
        int m = (int)ubuf[(size_t)tile * CAP + t];
        float tmx = kt[m] * KSCALE;
        float tmy = kt[MM + m] * KSCALE;
        float bx = floorf(tmx), by = floorf(tmy);
#pragma unroll
        for (int o = 0; o < 6; ++o) {
            float offv = (float)(o - 2);
            wts[t][o]     = kb_weight(tmx - (bx + offv));
            wts[t][6 + o] = kb_weight(tmy - (by + offv));
        }
        int lx = (int)bx & 15;
        int ly = (int)by & 15;
        lxy[t] = (lx << 8) | ly;
    }
    __syncthreads();
    int g = t >> 6;                    // bc pair: 2g, 2g+1
    int bcA = 2 * g, bcB = 2 * g + 1;
    for (int s = (t & 63); s < n; s += 64) {
        int m = (int)ubuf[(size_t)tile * CAP + s];
        float w0v[6], w1v[6];
#pragma unroll
        for (int o = 0; o < 6; ++o) {
            w0v[o] = wts[s][o];
            w1v[o] = wts[s][6 + o];
        }
        int lc = lxy[s];
        int lx = lc >> 8, ly = lc & 255;
        float ar0 = 0.0f, ai0 = 0.0f, ar1 = 0.0f, ai1 = 0.0f;
#pragma unroll
        for (int ii = 0; ii < 6; ++ii) {
            float wi = w0v[ii];
#pragma unroll
            for (int j = 0; j < 6; ++j) {
                float wv = wi * w1v[j];
                float2 va = lds_d[bcA][lx + ii][ly + j];
                float2 vb = lds_d[bcB][lx + ii][ly + j];
                ar0 = fmaf(wv, va.x, ar0);
                ai0 = fmaf(wv, va.y, ai0);
                ar1 = fmaf(wv, vb.x, ar1);
                ai1 = fmaf(wv, vb.y, ai1);
            }
        }
        out[(size_t)(bc0 + bcA) * MM + m] = make_float2(ar0, ai0);
        out[(size_t)(bc0 + bcB) * MM + m] = make_float2(ar1, ai1);
    }
}

// Fallback gather if ws is too small.
__global__ void k_gather(const float2* __restrict__ Xk, const float* __restrict__ kt,
                         float2* __restrict__ out) {
    int tid = blockIdx.x * blockDim.x + threadIdx.x;
    int m = tid & (MM - 1);
    int bc = tid >> 16;
    float tmx = kt[m] * KSCALE;
    float tmy = kt[MM + m] * KSCALE;
    float bx = floorf(tmx), by = floorf(tmy);
    int ibx = (int)bx, iby = (int)by;
    float w0[6], w1[6];
    int ix[6], iy[6];
#pragma unroll
    for (int o = 0; o < 6; ++o) {
        float offv = (float)(o - 2);
        w0[o] = kb_weight(tmx - (bx + offv));
        w1[o] = kb_weight(tmy - (by + offv));
        ix[o] = (ibx + (o - 2) + GSZ) & (GSZ - 1);
        iy[o] = (iby + (o - 2) + GSZ) & (GSZ - 1);
    }
    const float2* img = Xk + (size_t)bc * GG;
    float ar = 0.0f, ai = 0.0f;
#pragma unroll
    for (int i = 0; i < 6; ++i) {
        const float2* rowp = img + (size_t)ix[i] * GSZ;
        float wi = w0[i];
#pragma unroll
        for (int j = 0; j < 6; ++j) {
            float2 v = rowp[iy[j]];
            float wv = wi * w1[j];
            ar = fmaf(wv, v.x, ar);
            ai = fmaf(wv, v.y, ai);
        }
    }
    out[(size_t)bc * MM + m] = make_float2(ar, ai);
}

// ---------------- launch ----------------

extern "C" void kernel_launch(void* const* d_in, const int* in_sizes, int n_in,
                              void* d_out, int out_size, void* d_ws, size_t ws_size,
                              hipStream_t stream) {
    const float* x = (const float*)d_in[0];
    const float* kt = (const float*)d_in[1];
    float2* out = (float2*)d_out;
    char* ws = (char*)d_ws;

    const size_t GRID_BYTES = (size_t)BC * GG * sizeof(float2);      // 33.55 MB
    const size_t CNT_BYTES = 1024 * sizeof(unsigned);                // 4 KB
    const size_t UBUF_BYTES = (size_t)1024 * CAP * sizeof(unsigned short); // 320 KB
    float2* grid = (float2*)ws;
    unsigned* cnt = (unsigned*)(ws + GRID_BYTES);
    unsigned short* ubuf = (unsigned short*)(ws + GRID_BYTES + CNT_BYTES);
    const size_t NEED = GRID_BYTES + CNT_BYTES + UBUF_BYTES;

    if (ws_size >= NEED) {
        hipMemsetAsync(cnt, 0, CNT_BYTES, stream);
        k_bin<<<MM / 256, 256, 0, stream>>>(kt, cnt, ubuf);
        k_fft_row<<<BC * 64, 256, 0, stream>>>(x, grid);
        k_fft_col<<<BC * (GSZ / 16), 256, 0, stream>>>(grid);
        k_gather_tile<<<2 * 1024, 256, 0, stream>>>(grid, kt, cnt, ubuf, out);
    } else {
        k_fft_row<<<BC * 64, 256, 0, stream>>>(x, grid);
        k_fft_col<<<BC * (GSZ / 16), 256, 0, stream>>>(grid);
        k_gather<<<(BC * MM) / 256, 256, 0, stream>>>(grid, kt, out);
    }
}

// Round 8
// 85.258 us; speedup vs baseline: 1.5689x; 1.1167x over previous
//
#include <hip/hip_runtime.h>
#include <math.h>

// Problem constants (match reference)
#define NN 256
#define GSZ 512
#define GG (GSZ * GSZ)
#define BC 16            // B*C
#define MM 65536
#define ALPHA_C 14.04f   // 2.34 * W
#define WKER 6
#define PI_F 3.14159265358979f
#define RC2 0.70710678118654752f
#define KSCALE 81.48733086305042f  // GSZ / (2*pi)

// Gather tiling: 16x16 cells, 1024 tiles, ~64 pts/tile
#define CAP 160          // bucket capacity (mean 64, sd 8)
#define TW 21            // stencil region rows per tile (16 + 5)
#define TCW 22           // stored cols (21 + 1 pitch)
#define BCH 8            // bc images per unit (tile split over 2 halves)
#define NELEM (BCH * TW * TCW)   // 3696 float2 per unit

// ---------------- device math helpers ----------------

__device__ __forceinline__ float bessel_i0(float x) {
    if (x < 3.75f) {
        float t = x * (1.0f / 3.75f);
        float t2 = t * t;
        return 1.0f + t2 * (3.5156229f + t2 * (3.0899424f + t2 * (1.2067492f +
                     t2 * (0.2659732f + t2 * (0.0360768f + t2 * 0.0045813f)))));
    } else {
        float t = 3.75f / x;
        float p = 0.39894228f + t * (0.01328592f + t * (0.00225319f + t * (-0.00157565f +
                  t * (0.00916281f + t * (-0.02057706f + t * (0.02635537f +
                  t * (-0.01647633f + t * 0.00392377f)))))));
        return p * __expf(x) * rsqrtf(x);
    }
}

__device__ __forceinline__ float kb_weight(float d) {
    float r = d * (2.0f / (float)WKER);
    float u = 1.0f - r * r;
    if (u <= 0.0f) return 0.0f;
    return bessel_i0(ALPHA_C * sqrtf(u)) * (1.0f / (float)WKER);
}

__device__ __forceinline__ float kb_ft_inv(float t) {
    float a = PI_F * (float)WKER * t;
    float s2 = ALPHA_C * ALPHA_C - a * a;
    float z = sqrtf(fabsf(s2)) + 1e-12f;
    float sh = 0.5f * (__expf(z) - __expf(-z));
    return z / sh;
}

__device__ __forceinline__ void cmul(float& zr, float& zi, float wr, float wi) {
    float r = zr * wr - zi * wi;
    zi = zr * wi + zi * wr;
    zr = r;
}

// ---------------- radix-8 stage (in-place on one 512-pt plane pair) ----------
// Data lives at phi(i) = i + (i>>3). Stage combines 8 sub-DFTs of length L.
template <int L>
__device__ __forceinline__ void radix8_stage(float* pr, float* pi_, int j) {
    int pos = j & (L - 1);
    int base = (j - pos) * 8 + pos;
    float ar[8], ai[8];
#pragma unroll
    for (int r = 0; r < 8; ++r) {
        int idx = base + r * L;
        int ph = idx + (idx >> 3);
        ar[r] = pr[ph];
        ai[r] = pi_[ph];
    }
    if (L > 1) {
        float th = (float)pos * (-PI_F / (4.0f * (float)L));
        float s1, c1;
        __sincosf(th, &s1, &c1);
        float wr = c1, wi = s1;
#pragma unroll
        for (int r = 1; r < 8; ++r) {
            cmul(ar[r], ai[r], wr, wi);
            float nr = wr * c1 - wi * s1;
            wi = wr * s1 + wi * c1;
            wr = nr;
        }
    }
    float s0r = ar[0] + ar[4], s0i = ai[0] + ai[4];
    float d0r = ar[0] - ar[4], d0i = ai[0] - ai[4];
    float s1r = ar[2] + ar[6], s1i = ai[2] + ai[6];
    float d1r = ar[2] - ar[6], d1i = ai[2] - ai[6];
    float E0r = s0r + s1r, E0i = s0i + s1i;
    float E2r = s0r - s1r, E2i = s0i - s1i;
    float E1r = d0r + d1i, E1i = d0i - d1r;
    float E3r = d0r - d1i, E3i = d0i + d1r;
    float u0r = ar[1] + ar[5], u0i = ai[1] + ai[5];
    float v0r = ar[1] - ar[5], v0i = ai[1] - ai[5];
    float u1r = ar[3] + ar[7], u1i = ai[3] + ai[7];
    float v1r = ar[3] - ar[7], v1i = ai[3] - ai[7];
    float O0r = u0r + u1r, O0i = u0i + u1i;
    float O2r = u0r - u1r, O2i = u0i - u1i;
    float O1r = v0r + v1i, O1i = v0i - v1r;
    float O3r = v0r - v1i, O3i = v0i + v1r;
    float t1r = RC2 * (O1r + O1i), t1i = RC2 * (O1i - O1r);
    float t2r = O2i,               t2i = -O2r;
    float t3r = RC2 * (O3i - O3r), t3i = -RC2 * (O3r + O3i);
    float xr[8], xi[8];
    xr[0] = E0r + O0r; xi[0] = E0i + O0i;
    xr[4] = E0r - O0r; xi[4] = E0i - O0i;
    xr[1] = E1r + t1r; xi[1] = E1i + t1i;
    xr[5] = E1r - t1r; xi[5] = E1i - t1i;
    xr[2] = E2r + t2r; xi[2] = E2i + t2i;
    xr[6] = E2r - t2r; xi[6] = E2i - t2i;
    xr[3] = E3r + t3r; xi[3] = E3i + t3i;
    xr[7] = E3r - t3r; xi[7] = E3i - t3i;
#pragma unroll
    for (int q = 0; q < 8; ++q) {
        int idx = base + q * L;
        int ph = idx + (idx >> 3);
        pr[ph] = xr[q];
        pi_[ph] = xi[q];
    }
}

// ---------------- FFT kernels (radix-8, 3 stages) ----------------

#define LDSP 576
__global__ void __launch_bounds__(256) k_fft_row(const float* __restrict__ x,
                                                 float2* __restrict__ grid) {
    __shared__ float re[4][LDSP], im[4][LDSP];
    int b = blockIdx.x;
    int t = threadIdx.x;
    int w = t >> 6;
    int l = t & 63;
    int rg = (b & 63) * 4 + w;
    int bc = b >> 6;
    int r = (rg < 128) ? rg : rg + 256;
    int r_img = rg ^ 128;
    float scx = kb_ft_inv((float)(r_img - 128) * (1.0f / (float)GSZ));
    const float* xrow = x + ((size_t)bc * NN + (size_t)r_img) * NN;
#pragma unroll
    for (int e = 0; e < 8; ++e) {
        int i = e * 64 + l;
        float v = 0.0f;
        if (i < 128 || i >= 384) {
            int y = (i + 128) & (GSZ - 1);
            float scy = kb_ft_inv((float)(y - 128) * (1.0f / (float)GSZ));
            v = xrow[y] * scx * scy;
        }
        int rev = (l & 7) * 64 + (l >> 3) * 8 + e;
        int ph = rev + (rev >> 3);
        re[w][ph] = v;
        im[w][ph] = 0.0f;
    }
    __syncthreads();
    radix8_stage<1>(re[w], im[w], l);
    __syncthreads();
    radix8_stage<8>(re[w], im[w], l);
    __syncthreads();
    radix8_stage<64>(re[w], im[w], l);
    __syncthreads();
    size_t gbase = (size_t)bc * GG + (size_t)r * GSZ;
#pragma unroll
    for (int e = 0; e < 8; ++e) {
        int k = e * 64 + l;
        int ph = k + (k >> 3);
        grid[gbase + k] = make_float2(re[w][ph], im[w][ph]);
    }
}

#define CSTR 577
__global__ void __launch_bounds__(256) k_fft_col(float2* __restrict__ grid) {
    __shared__ float re[16][CSTR], im[16][CSTR];
    int b = blockIdx.x;
    int bc = b >> 5;
    int c0 = (b & 31) << 4;
    size_t base = (size_t)bc * GG + (size_t)c0;
    int t = threadIdx.x;
#pragma unroll
    for (int it = 0; it < 32; ++it) {
        int idx = it * 256 + t;
        int row = idx >> 4, col = idx & 15;
        float2 v = make_float2(0.0f, 0.0f);
        if (row < 128 || row >= 384)
            v = grid[base + (size_t)row * GSZ + col];
        int rev = (row & 7) * 64 + ((row >> 3) & 7) * 8 + (row >> 6);
        int ph = rev + (rev >> 3);
        re[col][ph] = v.x;
        im[col][ph] = v.y;
    }
    __syncthreads();
    int col = t & 15, jg = t >> 4;
#pragma unroll
    for (int k = 0; k < 4; ++k) radix8_stage<1>(re[col], im[col], jg + 16 * k);
    __syncthreads();
#pragma unroll
    for (int k = 0; k < 4; ++k) radix8_stage<8>(re[col], im[col], jg + 16 * k);
    __syncthreads();
#pragma unroll
    for (int k = 0; k < 4; ++k) radix8_stage<64>(re[col], im[col], jg + 16 * k);
    __syncthreads();
#pragma unroll
    for (int it = 0; it < 32; ++it) {
        int idx = it * 256 + t;
        int row = idx >> 4, c = idx & 15;
        int ph = row + (row >> 3);
        grid[base + (size_t)row * GSZ + c] = make_float2(re[c][ph], im[c][ph]);
    }
}

// ---------------- binning ----------------

__global__ void k_bin(const float* __restrict__ kt, unsigned* __restrict__ cnt,
                      unsigned short* __restrict__ ubuf) {
    int m = blockIdx.x * blockDim.x + threadIdx.x;
    float tmx = kt[m] * KSCALE;
    float tmy = kt[MM + m] * KSCALE;
    int ibx = (int)floorf(tmx) & (GSZ - 1);
    int iby = (int)floorf(tmy) & (GSZ - 1);
    int tile = ((ibx >> 4) << 5) | (iby >> 4);
    unsigned slot = atomicAdd(&cnt[tile], 1u);
    if (slot < CAP) ubuf[(size_t)tile * CAP + slot] = (unsigned short)m;
}

// ---------------- pipelined LDS-staged tile gather ----------------
// 512 blocks x 4 units; unit u = tile*2 + half (half = 8 bc images).
// Register double-buffer: regs hold unit u's staged region while LDS serves
// unit u-1's compute; next loads issue before phase-C (T14 async-stage).

__device__ __forceinline__ void load_unit(const float2* __restrict__ Xk, int u,
                                          int t, float2* buf) {
    int tile = u >> 1;
    int bc0 = (u & 1) * BCH;
    int tx0 = (tile >> 5) << 4;
    int ty0 = (tile & 31) << 4;
#pragma unroll
    for (int k = 0; k < 15; ++k) {
        int idx = t + (k << 8);
        if (idx < NELEM) {
            int bc = idx / (TW * TCW);
            int rem = idx - bc * (TW * TCW);
            int r = rem / TCW;
            int c = rem - r * TCW;
            int row = (tx0 - 2 + r) & (GSZ - 1);
            int col = (ty0 - 2 + c) & (GSZ - 1);
            buf[k] = Xk[(size_t)(bc0 + bc) * GG + (size_t)row * GSZ + col];
        }
    }
}

__global__ void __launch_bounds__(256) k_gather_tile(
    const float2* __restrict__ Xk, const float* __restrict__ kt,
    const unsigned* __restrict__ cnt, const unsigned short* __restrict__ ubuf,
    float2* __restrict__ out) {
    __shared__ float2 lds_d[BCH][TW][TCW];  // 29568 B
    __shared__ float wts[CAP][13];          // 8320 B
    __shared__ unsigned lxy[CAP];           // 640 B
    int bid = blockIdx.x;
    int b = ((bid & 7) << 6) | (bid >> 3);  // bijective XCD swizzle (512 = 8*64)
    int t = threadIdx.x;
    float2 buf[15];
    load_unit(Xk, 4 * b, t, buf);
    for (int k4 = 0; k4 < 4; ++k4) {
        int u = 4 * b + k4;
        int tile = u >> 1;
        int bc0 = (u & 1) * BCH;
        int n = (int)cnt[tile];
        if (n > CAP) n = CAP;
        __syncthreads();                    // prev phase-C done reading LDS
        float2* ldslin = &lds_d[0][0][0];
#pragma unroll
        for (int k = 0; k < 15; ++k) {
            int idx = t + (k << 8);
            if (idx < NELEM) ldslin[idx] = buf[k];
        }
        if ((k4 & 1) == 0 && t < n) {       // weights only when tile changes
            int m = (int)ubuf[(size_t)tile * CAP + t];
            float tmx = kt[m] * KSCALE;
            float tmy = kt[MM + m] * KSCALE;
            float bx = floorf(tmx), by = floorf(tmy);
#pragma unroll
            for (int o = 0; o < 6; ++o) {
                float offv = (float)(o - 2);
                wts[t][o]     = kb_weight(tmx - (bx + offv));
                wts[t][6 + o] = kb_weight(tmy - (by + offv));
            }
            int lx = (int)bx & 15;
            int ly = (int)by & 15;
            lxy[t] = ((unsigned)m << 8) | (unsigned)(lx << 4) | (unsigned)ly;
        }
        __syncthreads();
        if (k4 < 3) load_unit(Xk, u + 1, t, buf);   // async: consumed next iter
        int g = t >> 6;
        int bcA = 2 * g, bcB = 2 * g + 1;
        for (int s = (t & 63); s < n; s += 64) {
            unsigned lc = lxy[s];
            int m = (int)(lc >> 8);
            int lx = (int)((lc >> 4) & 15u);
            int ly = (int)(lc & 15u);
            float w0v[6], w1v[6];
#pragma unroll
            for (int o = 0; o < 6; ++o) {
                w0v[o] = wts[s][o];
                w1v[o] = wts[s][6 + o];
            }
            float ar0 = 0.0f, ai0 = 0.0f, ar1 = 0.0f, ai1 = 0.0f;
#pragma unroll
            for (int ii = 0; ii < 6; ++ii) {
                float wi = w0v[ii];
#pragma unroll
                for (int j = 0; j < 6; ++j) {
                    float wv = wi * w1v[j];
                    float2 va = lds_d[bcA][lx + ii][ly + j];
                    float2 vb = lds_d[bcB][lx + ii][ly + j];
                    ar0 = fmaf(wv, va.x, ar0);
                    ai0 = fmaf(wv, va.y, ai0);
                    ar1 = fmaf(wv, vb.x, ar1);
                    ai1 = fmaf(wv, vb.y, ai1);
                }
            }
            out[(size_t)(bc0 + bcA) * MM + m] = make_float2(ar0, ai0);
            out[(size_t)(bc0 + bcB) * MM + m] = make_float2(ar1, ai1);
        }
    }
}

// Fallback gather if ws is too small.
__global__ void k_gather(const float2* __restrict__ Xk, const float* __restrict__ kt,
                         float2* __restrict__ out) {
    int tid = blockIdx.x * blockDim.x + threadIdx.x;
    int m = tid & (MM - 1);
    int bc = tid >> 16;
    float tmx = kt[m] * KSCALE;
    float tmy = kt[MM + m] * KSCALE;
    float bx = floorf(tmx), by = floorf(tmy);
    int ibx = (int)bx, iby = (int)by;
    float w0[6], w1[6];
    int ix[6], iy[6];
#pragma unroll
    for (int o = 0; o < 6; ++o) {
        float offv = (float)(o - 2);
        w0[o] = kb_weight(tmx - (bx + offv));
        w1[o] = kb_weight(tmy - (by + offv));
        ix[o] = (ibx + (o - 2) + GSZ) & (GSZ - 1);
        iy[o] = (iby + (o - 2) + GSZ) & (GSZ - 1);
    }
    const float2* img = Xk + (size_t)bc * GG;
    float ar = 0.0f, ai = 0.0f;
#pragma unroll
    for (int i = 0; i < 6; ++i) {
        const float2* rowp = img + (size_t)ix[i] * GSZ;
        float wi = w0[i];
#pragma unroll
        for (int j = 0; j < 6; ++j) {
            float2 v = rowp[iy[j]];
            float wv = wi * w1[j];
            ar = fmaf(wv, v.x, ar);
            ai = fmaf(wv, v.y, ai);
        }
    }
    out[(size_t)bc * MM + m] = make_float2(ar, ai);
}

// ---------------- launch ----------------

extern "C" void kernel_launch(void* const* d_in, const int* in_sizes, int n_in,
                              void* d_out, int out_size, void* d_ws, size_t ws_size,
                              hipStream_t stream) {
    const float* x = (const float*)d_in[0];
    const float* kt = (const float*)d_in[1];
    float2* out = (float2*)d_out;
    char* ws = (char*)d_ws;

    const size_t GRID_BYTES = (size_t)BC * GG * sizeof(float2);      // 33.55 MB
    const size_t CNT_BYTES = 1024 * sizeof(unsigned);                // 4 KB
    const size_t UBUF_BYTES = (size_t)1024 * CAP * sizeof(unsigned short); // 320 KB
    float2* grid = (float2*)ws;
    unsigned* cnt = (unsigned*)(ws + GRID_BYTES);
    unsigned short* ubuf = (unsigned short*)(ws + GRID_BYTES + CNT_BYTES);
    const size_t NEED = GRID_BYTES + CNT_BYTES + UBUF_BYTES;

    if (ws_size >= NEED) {
        hipMemsetAsync(cnt, 0, CNT_BYTES, stream);
        k_bin<<<MM / 256, 256, 0, stream>>>(kt, cnt, ubuf);
        k_fft_row<<<BC * 64, 256, 0, stream>>>(x, grid);
        k_fft_col<<<BC * (GSZ / 16), 256, 0, stream>>>(grid);
        k_gather_tile<<<512, 256, 0, stream>>>(grid, kt, cnt, ubuf, out);
    } else {
        k_fft_row<<<BC * 64, 256, 0, stream>>>(x, grid);
        k_fft_col<<<BC * (GSZ / 16), 256, 0, stream>>>(grid);
        k_gather<<<(BC * MM) / 256, 256, 0, stream>>>(grid, kt, out);
    }
}